// Round 1
// baseline (112.529 us; speedup 1.0000x reference)
//

#include <hip/hip_runtime.h>

// RadiusInteractionGraph: B=128 molecules x 512 atoms, K=32 NN, cutoff 10.
// d_out is FLOAT32: [E] src ++ [E] dst ++ [E] weight, E = 128*512*32.
//
// R22 = R21 (truncated rank-select + bitonic-64, PASS @ 48us kernel) with the
// dual-row interleave widened to QUAD-row. R21 counters (VALUBusy 76%, no
// pipe saturated, VGPR=28) still show dependency-latency: the bit loop is a
// serial VALU->SALU->VALU chain, the sort a serial shfl chain; 24% of cycles
// are un-hidden stall. Four independent rows per wave (the wave's whole
// 4-row slice, rp loop removed) fill each other's stall slots; one atoms[j]
// ds_read_b128 now feeds 4 rows' distance math (LDS reads halved) and the
// bitonic keepmin predicate is computed once per step for all 4 chains.
// Epilogue uses BOTH wave halves: rows 0/1 on lanes 0-31, rows 2/3 on lanes
// 32-63 via one shfl_xor(32) per row (was: upper half idle).
// Selection semantics bit-identical to R21: key=(d2_hi23|j) lex == lax.top_k
// stable order; exact __f*_rn np arithmetic; sentinel 0x7F800000|j -> pad
// self-edge; W>64 fallback refines exactly (unconditional correctness).

constexpr int EDGES = 128 * 512 * 32;   // 2097152

static __device__ __forceinline__ unsigned umin2(unsigned a, unsigned b) {
    return a < b ? a : b;
}
static __device__ __forceinline__ unsigned umax2(unsigned a, unsigned b) {
    return a > b ? a : b;
}

static __device__ __forceinline__ unsigned mbcnt64(unsigned long long m) {
    return __builtin_amdgcn_mbcnt_hi(
        (unsigned)(m >> 32),
        __builtin_amdgcn_mbcnt_lo((unsigned)m, 0u));
}

static __device__ __forceinline__ unsigned count_lt8(const unsigned q[8],
                                                     unsigned C) {
    unsigned cnt = 0;
#pragma unroll
    for (int c = 0; c < 8; ++c)
        cnt += (unsigned)__popcll(__ballot(q[c] < C));
    return cnt;
}

// xor-partner fetch: strides 1,2 via DPP quad_perm (VALU); 4..32 via shfl.
template <int J>
static __device__ __forceinline__ unsigned xpart(unsigned v) {
    if (J == 1) {
        return (unsigned)__builtin_amdgcn_update_dpp(
            (int)v, (int)v, 0xB1, 0xF, 0xF, false);   // quad_perm(1,0,3,2)
    } else if (J == 2) {
        return (unsigned)__builtin_amdgcn_update_dpp(
            (int)v, (int)v, 0x4E, 0xF, 0xF, false);   // quad_perm(2,3,0,1)
    }
    return (unsigned)__shfl_xor((int)v, J, 64);
}

// one bitonic step applied to 4 independent chains (partner fetches batched
// so the 4 shfl/DPP latencies overlap; keepmin computed once).
template <int K, int J>
static __device__ __forceinline__ void bstep4(unsigned v[4], int lane) {
    unsigned p[4];
#pragma unroll
    for (int r = 0; r < 4; ++r) p[r] = xpart<J>(v[r]);
    const bool keepmin = (((lane & J) == 0) == ((lane & K) == 0));
#pragma unroll
    for (int r = 0; r < 4; ++r) {
        const unsigned mn = umin2(v[r], p[r]);
        const unsigned mx = umax2(v[r], p[r]);
        v[r] = keepmin ? mn : mx;
    }
}

// full ascending bitonic sort of 64 lanes, 4 chains interleaved
static __device__ __forceinline__ void bitonic64_4(unsigned v[4], int lane) {
    bstep4<2, 1>(v, lane);
    bstep4<4, 2>(v, lane);  bstep4<4, 1>(v, lane);
    bstep4<8, 4>(v, lane);  bstep4<8, 2>(v, lane);  bstep4<8, 1>(v, lane);
    bstep4<16, 8>(v, lane); bstep4<16, 4>(v, lane); bstep4<16, 2>(v, lane);
    bstep4<16, 1>(v, lane);
    bstep4<32, 16>(v, lane); bstep4<32, 8>(v, lane); bstep4<32, 4>(v, lane);
    bstep4<32, 2>(v, lane);  bstep4<32, 1>(v, lane);
    bstep4<64, 32>(v, lane); bstep4<64, 16>(v, lane); bstep4<64, 8>(v, lane);
    bstep4<64, 4>(v, lane);  bstep4<64, 2>(v, lane);  bstep4<64, 1>(v, lane);
}

__global__ __launch_bounds__(256)
void RadiusInteractionGraph_73246372266582_kernel(const float* __restrict__ pos,
                                                  float* __restrict__ out) {
    __shared__ float4 atoms[512];        // x, y, z, |p|^2
    __shared__ unsigned wbuf[4][4][64];  // per-wave, per-row window buffer

    const int tid     = threadIdx.x;
    const int b       = blockIdx.x >> 5;          // 32 blocks per molecule
    const int rowbase = (blockIdx.x & 31) * 16;   // 16 rows per block
    const int base    = b * 512;

    for (int a = tid; a < 512; a += 256) {
        float x = pos[(base + a) * 3 + 0];
        float y = pos[(base + a) * 3 + 1];
        float z = pos[(base + a) * 3 + 2];
        // np: sum(p*p) = (x*x + y*y) + z*z, sequential f32, no fma
        float sq = __fadd_rn(__fadd_rn(__fmul_rn(x, x), __fmul_rn(y, y)),
                             __fmul_rn(z, z));
        atoms[a] = make_float4(x, y, z, sq);
    }
    __syncthreads();

    const int wave = tid >> 6;
    const int lane = tid & 63;
    const int i0   = rowbase + (wave << 2);       // this wave's 4 rows

    const float4 c0 = atoms[i0 + 0];
    const float4 c1 = atoms[i0 + 1];
    const float4 c2 = atoms[i0 + 2];
    const float4 c3 = atoms[i0 + 3];

    // ---- build 8 UNIQUE keys per lane for all four rows (interleaved) ----
    unsigned q[4][8];
#pragma unroll
    for (int c = 0; c < 8; ++c) {
        const int j = c * 64 + lane;
        const float4 pj = atoms[j];               // one ds_read_b128, shared x4
#pragma unroll
        for (int r = 0; r < 4; ++r) {
            const float4 ci = (r == 0) ? c0 : (r == 1) ? c1 : (r == 2) ? c2 : c3;
            // np einsum order: ((xi*xj + yi*yj) + zi*zj), plain f32, no fma
            float dot = __fadd_rn(__fadd_rn(__fmul_rn(ci.x, pj.x),
                                            __fmul_rn(ci.y, pj.y)),
                                  __fmul_rn(ci.z, pj.z));
            float d2 = __fsub_rn(__fadd_rn(ci.w, pj.w), __fmul_rn(2.0f, dot));
            d2 = fmaxf(d2, 0.0f);
            q[r][c] = ((j != i0 + r) && (d2 <= 100.0f))
                          ? ((__float_as_uint(d2) & 0xFFFFFE00u) | (unsigned)j)
                          : (0x7F800000u | (unsigned)j);
        }
    }

    // ---- truncated greedy MSB rank bound, 4 rows interleaved (bits 30..21) --
    unsigned X[4] = {0u, 0u, 0u, 0u};
    for (int bit = 30; bit >= 21; --bit) {
        unsigned C[4];
#pragma unroll
        for (int r = 0; r < 4; ++r) C[r] = X[r] | (1u << bit);
        unsigned n0 = 0, n1 = 0, n2 = 0, n3 = 0;
#pragma unroll
        for (int c = 0; c < 8; ++c) {
            n0 += (unsigned)__popcll(__ballot(q[0][c] < C[0]));
            n1 += (unsigned)__popcll(__ballot(q[1][c] < C[1]));
            n2 += (unsigned)__popcll(__ballot(q[2][c] < C[2]));
            n3 += (unsigned)__popcll(__ballot(q[3][c] < C[3]));
        }
        if (n0 < 32u) X[0] = C[0];
        if (n1 < 32u) X[1] = C[1];
        if (n2 < 32u) X[2] = C[2];
        if (n3 < 32u) X[3] = C[3];
    }

    unsigned hi[4], W[4];
#pragma unroll
    for (int r = 0; r < 4; ++r) {
        hi[r] = X[r] + (1u << 21);
        W[r]  = count_lt8(q[r], hi[r]);
    }
#pragma unroll
    for (int r = 0; r < 4; ++r) {
        if (W[r] > 64u) {   // pathological: refine exactly (R19 path)
            for (int bit = 20; bit >= 0; --bit) {
                const unsigned C = X[r] | (1u << bit);
                if (count_lt8(q[r], C) < 32u) X[r] = C;
            }
            hi[r] = X[r] + 1u;
        }
    }

    // ---- compact all four windows (ballot+mbcnt), sentinel-pad to 64 ----
#pragma unroll
    for (int r = 0; r < 4; ++r) wbuf[wave][r][lane] = 0xFFFFFFFFu;
    unsigned t[4] = {0u, 0u, 0u, 0u};
#pragma unroll
    for (int c = 0; c < 8; ++c) {
#pragma unroll
        for (int r = 0; r < 4; ++r) {
            const bool s = (q[r][c] < hi[r]);
            const unsigned long long m = __ballot(s);
            const unsigned o = t[r] + mbcnt64(m);
            if (s) wbuf[wave][r][o] = q[r][c];
            t[r] += (unsigned)__popcll(m);
        }
    }

    unsigned v[4];
#pragma unroll
    for (int r = 0; r < 4; ++r) v[r] = wbuf[wave][r][lane];  // per-wave: in-order

    // ---- four interleaved bitonic sort-64s (independent chains) ----
    bitonic64_4(v, lane);

    // ---- epilogue on BOTH halves: rows 0,1 -> lanes 0..31; rows 2,3 ->
    //      lanes 32..63 (results moved up via one shfl_xor(32) per row).
    //      coalesced 128 B per region per row half.
    const unsigned vu2 = (unsigned)__shfl_xor((int)v[2], 32, 64);
    const unsigned vu3 = (unsigned)__shfl_xor((int)v[3], 32, 64);
    const int half = lane >> 5;
    const int l32  = lane & 31;
#pragma unroll
    for (int s = 0; s < 2; ++s) {
        const unsigned vv = half ? (s ? vu3 : vu2) : (s ? v[1] : v[0]);
        const int gi   = i0 + (half << 1) + s;    // center atom (local idx)
        const int gdst = base + gi;
        const float4 ci = atoms[gi];              // 2 addrs/wave, broadcast
        float w = 0.0f;
        float srcf = (float)gdst;                 // sentinel -> self-edge, w=0
        if (vv < 0x7F800000u) {
            const int j = (int)(vv & 511u);
            const float4 pj = atoms[j];
            float dot = __fadd_rn(__fadd_rn(__fmul_rn(ci.x, pj.x),
                                            __fmul_rn(ci.y, pj.y)),
                                  __fmul_rn(ci.z, pj.z));
            float d2 = __fsub_rn(__fadd_rn(ci.w, pj.w),
                                 __fmul_rn(2.0f, dot));
            d2 = fmaxf(d2, 0.0f);
            w = __fsqrt_rn(fmaxf(d2, 1e-12f));
            srcf = (float)(base + j);
        }
        const size_t eb = (size_t)gdst * 32 + (size_t)l32;
        out[eb]                     = srcf;          // src
        out[(size_t)EDGES + eb]     = (float)gdst;   // dst
        out[(size_t)EDGES * 2 + eb] = w;             // weight
    }
}

extern "C" void kernel_launch(void* const* d_in, const int* in_sizes, int n_in,
                              void* d_out, int out_size, void* d_ws, size_t ws_size,
                              hipStream_t stream) {
    (void)in_sizes; (void)n_in; (void)d_ws; (void)ws_size; (void)out_size;
    const float* pos = (const float*)d_in[0];   // [N,3] f32
    float* out       = (float*)d_out;           // [3E] f32

    RadiusInteractionGraph_73246372266582_kernel<<<dim3(4096), dim3(256), 0,
                                                   stream>>>(pos, out);
}